// Round 12
// baseline (1150.534 us; speedup 1.0000x reference)
//
#include <hip/hip_runtime.h>
#include <stdint.h>

#define Bb 128
#define Nn 1024
#define Dd 512
#define Ss 64

constexpr float kScale = 0.044194173824159216f;  // 512^-0.5
constexpr float kEps = 1e-8f;

typedef __bf16 bf16x8 __attribute__((ext_vector_type(8)));
typedef float f32x4 __attribute__((ext_vector_type(4)));
typedef float f32x16 __attribute__((ext_vector_type(16)));
typedef unsigned short ushort8 __attribute__((ext_vector_type(8)));

#define MFMA32 __builtin_amdgcn_mfma_f32_32x32x16_bf16

__device__ inline unsigned short f2bf_rne(float x) {
  unsigned u = __builtin_bit_cast(unsigned, x);
  u += 0x7FFFu + ((u >> 16) & 1u);
  return (unsigned short)(u >> 16);
}
__device__ inline float bf2f(unsigned short h) {
  unsigned u = ((unsigned)h) << 16;
  return __builtin_bit_cast(float, u);
}

// async global->LDS, 16B per lane; LDS dest must be wave-uniform base (HW adds lane*16)
__device__ inline void gl_lds16(const void* g, void* l) {
  typedef unsigned int u32;
  auto gp = (u32 __attribute__((address_space(1)))*)(unsigned long long)(uintptr_t)g;
  auto lp = (u32 __attribute__((address_space(3)))*)(unsigned int)(uintptr_t)l;
  __builtin_amdgcn_global_load_lds(gp, lp, 16, 0, 0);
}

// f32 -> INTERLEAVED split bf16: out[granule*16 + 0..7] = hi, [+8..15] = lo.
__global__ void cast_split_i(const float* __restrict__ in,
                             unsigned short* __restrict__ out, int n8) {
  int i = blockIdx.x * blockDim.x + threadIdx.x;
  const int stride = gridDim.x * blockDim.x;
  for (; i < n8; i += stride) {
    const float4 v0 = ((const float4*)in)[i * 2];
    const float4 v1 = ((const float4*)in)[i * 2 + 1];
    float f[8] = {v0.x, v0.y, v0.z, v0.w, v1.x, v1.y, v1.z, v1.w};
    ushort8 h, lo;
#pragma unroll
    for (int j = 0; j < 8; j++) {
      h[j] = f2bf_rne(f[j]);
      lo[j] = f2bf_rne(f[j] - bf2f(h[j]));
    }
    ((ushort8*)out)[i * 2] = h;
    ((ushort8*)out)[i * 2 + 1] = lo;
  }
}

// C[M,512] = act(A[M,512] @ W[512,512]^T + bias), FUSED 3-term split bf16.
// Interleaved split layout [row][1024 ushorts], granule g at g*16 (+0 hi, +8 lo).
// BM=BN=256, 8 waves (2Mx4N), wave-tile 128x64, 32x32x16 MFMA, K-half = 16.
// Ring-4 x 32KB LDS slots; m97-granularity staging (16 rows x 64B contiguous
// per gl_lds, 32B-pair swizzle inside the segment, linear LDS dest).
// Schedule = R9/R11 (race-fixed): lgkmcnt(0); vmcnt(counted); barrier;
// STG(h+4); READF(h+1); sched_bar; setprio(1) 24 MFMA setprio(0).
// R12: epilogue via per-wave LDS transpose -> 4x contiguous 16B stores per
// lane per 32x32 quadrant (was 128 scattered 2B stores).
template <int ACT>
__global__ __launch_bounds__(512, 1) void gemm_hp(
    const unsigned short* __restrict__ A, const unsigned short* __restrict__ W,
    const float* __restrict__ bias, unsigned short* __restrict__ C) {
  constexpr int NH = 32;  // K=512 / 16
  extern __shared__ unsigned short lds[];  // 4 x 16384 ushorts = 128KB
  const int t = threadIdx.x, l = t & 63, w = t >> 6;
  const int wr = w >> 2, wc = w & 3;

  // bijective XCD-chunked swizzle (1024 = 8 x 128); wg pairs share the A panel
  const int wg = ((blockIdx.x & 7) << 7) + (blockIdx.x >> 3);
  const long rowA0 = (long)(wg >> 1) * 256;
  const int colB0 = (wg & 1) * 256;

  // ---- staging: 32 chunks/slot (16 rows x 64B each); 4 chunks per wave ----
  const unsigned short* base8 = (w < 4) ? A + rowA0 * 1024 : W + (long)colB0 * 1024;
  const int p2s = ((l >> 1) ^ (l >> 4)) & 1;
  const unsigned short* srcp[4];
  int dstp[4];
#pragma unroll
  for (int j = 0; j < 4; j++) {
    const int cid = (w & 3) * 4 + j;
    srcp[j] = base8 + (long)(cid * 16 + (l >> 2)) * 1024 + p2s * 16 + (l & 1) * 8;
    dstp[j] = (w * 4 + j) * 512;  // + lane*8 implicit
  }
#define STG(h)                                                            \
  {                                                                       \
    unsigned short* bq_ = lds + ((h) & 3) * 16384;                        \
    _Pragma("unroll") for (int j = 0; j < 4; j++)                         \
        gl_lds16(srcp[j] + (h) * 32, bq_ + dstp[j]);                      \
  }

  // ---- frag reads: row = R0+(l&31), granule g = l>>5;
  // stored pair pos = g ^ ((row>>2)&1) = (l>>5) ^ ((l>>2)&1). hi +0, lo +8. ----
  const int pp16 = (((l >> 5) ^ ((l >> 2) & 1))) * 16;
  const int abase0 = (wr * 128 + (l & 31)) * 32 + pp16;          // A @0
  const int bbase0 = 8192 + (wc * 64 + (l & 31)) * 32 + pp16;    // W @8192

#define READF(h, S)                                                       \
  {                                                                       \
    const unsigned short* bq_ = lds + ((h) & 3) * 16384;                  \
    _Pragma("unroll") for (int m = 0; m < 4; m++) {                       \
      ah##S[m] = *(const bf16x8*)(bq_ + abase0 + m * 1024);               \
      al##S[m] = *(const bf16x8*)(bq_ + abase0 + m * 1024 + 8);           \
    }                                                                     \
    _Pragma("unroll") for (int n = 0; n < 2; n++) {                       \
      bh##S[n] = *(const bf16x8*)(bq_ + bbase0 + n * 1024);               \
      bl##S[n] = *(const bf16x8*)(bq_ + bbase0 + n * 1024 + 8);           \
    }                                                                     \
  }

#define MFMACL(S)                                                         \
  {                                                                       \
    _Pragma("unroll") for (int m = 0; m < 4; m++)                         \
        _Pragma("unroll") for (int n = 0; n < 2; n++) {                   \
      acc[m][n] = MFMA32(ah##S[m], bh##S[n], acc[m][n], 0, 0, 0);         \
      acc[m][n] = MFMA32(al##S[m], bh##S[n], acc[m][n], 0, 0, 0);         \
      acc[m][n] = MFMA32(ah##S[m], bl##S[n], acc[m][n], 0, 0, 0);         \
    }                                                                     \
  }

#define BODY(h, CUR, NXT)                                                 \
  {                                                                       \
    asm volatile("s_waitcnt lgkmcnt(0)" ::: "memory");                    \
    __builtin_amdgcn_sched_barrier(0);                                    \
    if ((h) < 29) {                                                       \
      asm volatile("s_waitcnt vmcnt(8)" ::: "memory");                    \
    } else if ((h) == 29) {                                               \
      asm volatile("s_waitcnt vmcnt(4)" ::: "memory");                    \
    } else if ((h) == 30) {                                               \
      asm volatile("s_waitcnt vmcnt(0)" ::: "memory");                    \
    }                                                                     \
    __builtin_amdgcn_s_barrier();                                         \
    if ((h) + 4 < NH) STG((h) + 4);                                       \
    if ((h) + 1 < NH) READF((h) + 1, NXT);                                \
    __builtin_amdgcn_sched_barrier(0);                                    \
    __builtin_amdgcn_s_setprio(1);                                        \
    MFMACL(CUR);                                                          \
    __builtin_amdgcn_s_setprio(0);                                        \
  }

  f32x16 acc[4][2] = {};
  bf16x8 ahA[4], alA[4], bhA[2], blA[2];
  bf16x8 ahB[4], alB[4], bhB[2], blB[2];

  STG(0); STG(1); STG(2); STG(3);
  asm volatile("s_waitcnt vmcnt(12)" ::: "memory");  // own stage(0) landed
  __builtin_amdgcn_s_barrier();                      // everyone's stage(0) landed
  READF(0, A);

  for (int hh = 0; hh < NH; hh += 2) {
    BODY(hh, A, B);
    BODY(hh + 1, B, A);
  }
#undef STG
#undef READF
#undef MFMACL
#undef BODY

  // ---- epilogue (R12): per-wave LDS transpose -> coalesced 16B stores ----
  // Safe without barrier: each wave's region is private, and no wave issues
  // further ring-buffer ds_reads after its final BODY.
  {
    float* ep = (float*)lds + w * 1152;  // 32x36 f32 region (4608B), 16B-aligned
    const int rr = l >> 1, ch = l & 1;   // read-back: row l>>1, col-half l&1
#pragma unroll
    for (int m = 0; m < 4; m++)
#pragma unroll
      for (int n = 0; n < 2; n++) {
        const int colbase = colB0 + wc * 64 + n * 32;
        const float bv = bias[colbase + (l & 31)];
#pragma unroll
        for (int r = 0; r < 16; r++) {
          const int lrow = (r & 3) + 8 * (r >> 2) + 4 * (l >> 5);
          float xv = acc[m][n][r] + bv;
          if (ACT) xv = fmaxf(xv, 0.0f);
          ep[lrow * 36 + (l & 31)] = xv;
        }
        asm volatile("s_waitcnt lgkmcnt(0)" ::: "memory");
        __builtin_amdgcn_sched_barrier(0);
        float vals[16];
#pragma unroll
        for (int q = 0; q < 4; q++)
          *(f32x4*)&vals[q * 4] = *(const f32x4*)(ep + rr * 36 + ch * 16 + q * 4);
        ushort8 outv[4];
#pragma unroll
        for (int g = 0; g < 2; g++)
#pragma unroll
          for (int j = 0; j < 8; j++) {
            const float v = vals[g * 8 + j];
            const unsigned short h = f2bf_rne(v);
            outv[g * 2][j] = h;
            outv[g * 2 + 1][j] = f2bf_rne(v - bf2f(h));
          }
        const long row = rowA0 + wr * 128 + m * 32 + rr;
        unsigned short* cp = C + row * 1024 + (colbase >> 3) * 16 + ch * 32;
#pragma unroll
        for (int q = 0; q < 4; q++) ((ushort8*)cp)[q] = outv[q];
        asm volatile("s_waitcnt lgkmcnt(0)" ::: "memory");  // region reuse guard
        __builtin_amdgcn_sched_barrier(0);
      }
  }
}

// dots[b,64,1024] = scale * slots[64,512] @ k[b,1024,512]^T  (interleaved split in)
__global__ __launch_bounds__(256) void gemm_dots_split(
    const unsigned short* __restrict__ QI, const unsigned short* __restrict__ KI,
    float* __restrict__ dots) {
  constexpr int K = 512, BM = 64, BN = 128, BK = 32;
  __shared__ __align__(16) unsigned short lah[BM * BK];
  __shared__ __align__(16) unsigned short lal[BM * BK];
  __shared__ __align__(16) unsigned short lbh[BN * BK];
  __shared__ __align__(16) unsigned short lbl[BN * BK];
  const int t = threadIdx.x, l = t & 63, w = t >> 6;
  const int b = blockIdx.x >> 3, bc = blockIdx.x & 7;
  const unsigned short* kb = KI + (long)b * Nn * 1024;
  f32x4 acc[4][2] = {};

  const int qbase = (t >> 2) * 1024 + (t & 3) * 16;
  const long kbase0 = (long)(bc * BN + (t >> 2)) * 1024 + (t & 3) * 16;
  const long kbase1 = (long)(bc * BN + 64 + (t >> 2)) * 1024 + (t & 3) * 16;

  for (int k0 = 0; k0 < K; k0 += BK) {
    const int ko = k0 * 2;  // ushort offset of granule (k0>>3)*16
    const int lo = w * 512;
    gl_lds16(QI + qbase + ko, lah + lo);
    gl_lds16(QI + qbase + ko + 8, lal + lo);
    gl_lds16(kb + kbase0 + ko, lbh + lo);
    gl_lds16(kb + kbase0 + ko + 8, lbl + lo);
    gl_lds16(kb + kbase1 + ko, lbh + 2048 + lo);
    gl_lds16(kb + kbase1 + ko + 8, lbl + 2048 + lo);
    __syncthreads();
    bf16x8 ah[4], al[4], bh[2], bl[2];
#pragma unroll
    for (int m = 0; m < 4; m++) {
      const int off = (m * 16 + (l & 15)) * BK + (l >> 4) * 8;
      ah[m] = *(const bf16x8*)(lah + off);
      al[m] = *(const bf16x8*)(lal + off);
    }
#pragma unroll
    for (int n = 0; n < 2; n++) {
      const int off = (w * 32 + n * 16 + (l & 15)) * BK + (l >> 4) * 8;
      bh[n] = *(const bf16x8*)(lbh + off);
      bl[n] = *(const bf16x8*)(lbl + off);
    }
#pragma unroll
    for (int m = 0; m < 4; m++)
#pragma unroll
      for (int n = 0; n < 2; n++) {
        acc[m][n] = __builtin_amdgcn_mfma_f32_16x16x32_bf16(ah[m], bh[n], acc[m][n], 0, 0, 0);
        acc[m][n] = __builtin_amdgcn_mfma_f32_16x16x32_bf16(al[m], bh[n], acc[m][n], 0, 0, 0);
        acc[m][n] = __builtin_amdgcn_mfma_f32_16x16x32_bf16(ah[m], bl[n], acc[m][n], 0, 0, 0);
      }
    __syncthreads();
  }
  float* dp = dots + (long)b * Ss * Nn;
#pragma unroll
  for (int m = 0; m < 4; m++) {
    const int row = m * 16 + (l >> 4) * 4;
#pragma unroll
    for (int n = 0; n < 2; n++) {
      const int col = bc * BN + w * 32 + n * 16 + (l & 15);
#pragma unroll
      for (int r = 0; r < 4; r++) dp[(long)(row + r) * Nn + col] = acc[m][n][r] * kScale;
    }
  }
}

// per-batch: s_j[b,i] = sum_j dots, s_all[b] = sum_ij dots (coalesced float4 + shfl)
__global__ __launch_bounds__(256) void reduce_k(
    const float* __restrict__ dots, float* __restrict__ s_j, float* __restrict__ s_all) {
  const int b = blockIdx.x, t = threadIdx.x, l = t & 63, w = t >> 6;
  const float4* dp = (const float4*)(dots + (long)b * Ss * Nn);
  __shared__ float rowacc[64][4];
  __shared__ float rowsum[64];
  for (int r = 0; r < 64; ++r) {
    const float4 v = dp[r * 256 + t];  // whole block reads row r, lane-contiguous
    float s = v.x + v.y + v.z + v.w;
#pragma unroll
    for (int off = 32; off; off >>= 1) s += __shfl_down(s, off);
    if (l == 0) rowacc[r][w] = s;
  }
  __syncthreads();
  if (t < 64) {
    const float v = rowacc[t][0] + rowacc[t][1] + rowacc[t][2] + rowacc[t][3];
    rowsum[t] = v;
    s_j[b * 64 + t] = v;
  }
  __syncthreads();
  if (t < 64) {
    float v = rowsum[t];
#pragma unroll
    for (int off = 32; off; off >>= 1) v += __shfl_down(v, off);
    if (t == 0) s_all[b] = v;
  }
}

// attn = sigmoid(dots * s_all/s_j) -> out; inv_r = 1/(rowsum(attn)+eps)
__global__ __launch_bounds__(256) void attn_k(
    const float* __restrict__ dots, const float* __restrict__ s_j,
    const float* __restrict__ s_all, float* __restrict__ attn_out,
    float* __restrict__ inv_r) {
  const int bi = blockIdx.x;
  const int b = bi >> 6;
  const int t = threadIdx.x;
  const float ratio = s_all[b] / s_j[bi];
  const float* dp = dots + (long)bi * Nn;
  float* ap = attn_out + (long)bi * Nn;
  float s = 0.f;
#pragma unroll
  for (int qq = 0; qq < 4; qq++) {
    const int j = qq * 256 + t;
    const float x = dp[j] * ratio;
    const float a = 1.f / (1.f + expf(-x));
    ap[j] = a;
    s += a;
  }
  __shared__ float red[256];
  red[t] = s;
  __syncthreads();
  for (int off = 128; off > 0; off >>= 1) {
    if (t < off) red[t] += red[t + off];
    __syncthreads();
  }
  if (t == 0) inv_r[bi] = 1.f / (red[0] + kEps);
}

// updates[b,i,d] = inv_r[b,i] * sum_j attn[b,i,j] * inputs[b,j,d]  (fp32 register tile)
__global__ __launch_bounds__(256, 1) void updates_k2(
    const float* __restrict__ attn, const float* __restrict__ inputs,
    const float* __restrict__ inv_r, float* __restrict__ out0) {
  constexpr int NT2 = 32;
  constexpr int BUF_F = 10240;
  extern __shared__ float ldsf[];
  const int t = threadIdx.x, lam = t & 63, w = t >> 6;
  const int b = blockIdx.x >> 1, dt = blockIdx.x & 1;
  const int ig = t >> 5, dg = t & 31;
  const float* inb = inputs + (size_t)b * (Nn * Dd) + dt * 256;
  const float* attsrc = attn + (size_t)b * (Ss * Nn) + (size_t)(t >> 2) * Nn + (t & 3) * 8;
  float acc[8][8] = {};
  float4 ga0, ga1, gb0, gb1;

#define UISSUE(bufi, tile, G0, G1)                                        \
  {                                                                       \
    const int j0_ = (tile)*32;                                            \
    G0 = *(const float4*)(attsrc + j0_);                                  \
    G1 = *(const float4*)(attsrc + j0_ + 4);                              \
    float* db_ = ldsf + (bufi)*BUF_F;                                     \
    _Pragma("unroll") for (int i_ = 0; i_ < 8; i_++) {                    \
      const int row_ = i_ * 4 + w;                                        \
      gl_lds16(inb + (size_t)(j0_ + row_) * Dd + lam * 4, db_ + row_ * 256); \
    }                                                                     \
  }

#define UWRITE(bufi, G0, G1)                                              \
  {                                                                       \
    float* ab_ = ldsf + (bufi)*BUF_F + 8192;                              \
    const int col_ = t >> 2;                                              \
    const int r0_ = (t & 3) * 8;                                          \
    ab_[(r0_ + 0) * 64 + col_] = G0.x;                                    \
    ab_[(r0_ + 1) * 64 + col_] = G0.y;                                    \
    ab_[(r0_ + 2) * 64 + col_] = G0.z;                                    \
    ab_[(r0_ + 3) * 64 + col_] = G0.w;                                    \
    ab_[(r0_ + 4) * 64 + col_] = G1.x;                                    \
    ab_[(r0_ + 5) * 64 + col_] = G1.y;                                    \
    ab_[(r0_ + 6) * 64 + col_] = G1.z;                                    \
    ab_[(r0_ + 7) * 64 + col_] = G1.w;                                    \
  }

#define UCOMP(bufi)                                                       \
  {                                                                       \
    const float* db_ = ldsf + (bufi)*BUF_F;                               \
    const float* ab_ = db_ + 8192;                                        \
    _Pragma("unroll 4") for (int jj = 0; jj < 32; jj++) {                 \
      float av[8], vv[8];                                                 \
      *(float4*)&av[0] = *(const float4*)(ab_ + jj * 64 + ig * 8);        \
      *(float4*)&av[4] = *(const float4*)(ab_ + jj * 64 + ig * 8 + 4);    \
      *(float4*)&vv[0] = *(const float4*)(db_ + jj * 256 + dg * 8);       \
      *(float4*)&vv[4] = *(const float4*)(db_ + jj * 256 + dg * 8 + 4);   \
      _Pragma("unroll") for (int m_ = 0; m_ < 8; m_++)                    \
          _Pragma("unroll") for (int n_ = 0; n_ < 8; n_++)                \
              acc[m_][n_] = __builtin_fmaf(av[m_], vv[n_], acc[m_][n_]);  \
    }                                                                     \
  }

  UISSUE(0, 0, ga0, ga1);
  UISSUE(1, 1, gb0, gb1);
  UWRITE(0, ga0, ga1);

  for (int tt = 0; tt < NT2; tt += 2) {
    asm volatile("s_waitcnt vmcnt(10)" ::: "memory");
    UWRITE((tt + 1) % 3, gb0, gb1);
    asm volatile("s_waitcnt lgkmcnt(0)" ::: "memory");
    __builtin_amdgcn_s_barrier();
    __builtin_amdgcn_sched_barrier(0);
    if (tt < NT2 - 2) UISSUE((tt + 2) % 3, tt + 2, ga0, ga1);
    UCOMP(tt % 3);
    if (tt + 1 < NT2 - 1) {
      asm volatile("s_waitcnt vmcnt(10)" ::: "memory");
    } else {
      asm volatile("s_waitcnt vmcnt(0)" ::: "memory");
    }
    if (tt + 1 < NT2 - 1) UWRITE((tt + 2) % 3, ga0, ga1);
    asm volatile("s_waitcnt lgkmcnt(0)" ::: "memory");
    __builtin_amdgcn_s_barrier();
    __builtin_amdgcn_sched_barrier(0);
    if (tt + 1 < NT2 - 2) UISSUE((tt + 3) % 3, tt + 3, gb0, gb1);
    UCOMP((tt + 1) % 3);
  }
#undef UISSUE
#undef UWRITE
#undef UCOMP

#pragma unroll
  for (int m = 0; m < 8; m++) {
    const int i = ig * 8 + m;
    const float ir = inv_r[b * 64 + i];
    float4 o0, o1;
    o0.x = acc[m][0] * ir; o0.y = acc[m][1] * ir; o0.z = acc[m][2] * ir; o0.w = acc[m][3] * ir;
    o1.x = acc[m][4] * ir; o1.y = acc[m][5] * ir; o1.z = acc[m][6] * ir; o1.w = acc[m][7] * ir;
    float* op = out0 + (size_t)(b * 64 + i) * Dd + dt * 256 + dg * 8;
    *(float4*)op = o0;
    *(float4*)(op + 4) = o1;
  }
}

extern "C" void kernel_launch(void* const* d_in, const int* in_sizes, int n_in,
                              void* d_out, int out_size, void* d_ws, size_t ws_size,
                              hipStream_t stream) {
  (void)in_sizes; (void)n_in; (void)out_size; (void)ws_size;
  const float* inputs_pe = (const float*)d_in[0];
  const float* inputs = (const float*)d_in[1];
  const float* slots = (const float*)d_in[2];
  const float* W1 = (const float*)d_in[3];
  const float* b1 = (const float*)d_in[4];
  const float* W2 = (const float*)d_in[5];
  const float* b2 = (const float*)d_in[6];
  const float* W3 = (const float*)d_in[7];
  const float* b3 = (const float*)d_in[8];

  char* ws = (char*)d_ws;
  size_t off = 0;
  auto alloc = [&](size_t bytes) -> void* {
    void* p = ws + off;
    off += (bytes + 255) & ~(size_t)255;
    return p;
  };
  const size_t actB = (size_t)Bb * Nn * 1024 * 2;  // interleaved split activation
  unsigned short* AI = (unsigned short*)alloc(actB);
  unsigned short* BI = (unsigned short*)alloc(actB);
  unsigned short* w1i = (unsigned short*)alloc(Dd * 1024 * 2);
  unsigned short* w2i = (unsigned short*)alloc(Dd * 1024 * 2);
  unsigned short* w3i = (unsigned short*)alloc(Dd * 1024 * 2);
  unsigned short* qi = (unsigned short*)alloc(Ss * 1024 * 2);
  float* dotsb = (float*)alloc((size_t)Bb * Ss * Nn * 4);
  float* s_j = (float*)alloc(Bb * Ss * 4);
  float* s_all = (float*)alloc(Bb * 4);
  float* inv_r = (float*)alloc(Bb * Ss * 4);

  float* out_updates = (float*)d_out;
  float* out_attn = out_updates + (size_t)Bb * Ss * Dd;

  const int kLdsG = 4 * 32 * 1024;  // 128KB ring-4 for gemm_hp (epilogue reuses it)
  const int kLdsU = 3 * 40 * 1024;  // 120KB for updates_k2
  hipFuncSetAttribute(reinterpret_cast<const void*>(gemm_hp<1>),
                      hipFuncAttributeMaxDynamicSharedMemorySize, kLdsG);
  hipFuncSetAttribute(reinterpret_cast<const void*>(gemm_hp<0>),
                      hipFuncAttributeMaxDynamicSharedMemorySize, kLdsG);
  hipFuncSetAttribute(reinterpret_cast<const void*>(updates_k2),
                      hipFuncAttributeMaxDynamicSharedMemorySize, kLdsU);

  cast_split_i<<<4096, 256, 0, stream>>>(inputs_pe, AI, Bb * Nn * Dd / 8);
  cast_split_i<<<128, 256, 0, stream>>>(W1, w1i, Dd * Dd / 8);
  cast_split_i<<<128, 256, 0, stream>>>(W2, w2i, Dd * Dd / 8);
  cast_split_i<<<128, 256, 0, stream>>>(W3, w3i, Dd * Dd / 8);
  cast_split_i<<<16, 256, 0, stream>>>(slots, qi, Ss * Dd / 8);

  gemm_hp<1><<<1024, 512, kLdsG, stream>>>(AI, w1i, b1, BI);
  gemm_hp<1><<<1024, 512, kLdsG, stream>>>(BI, w2i, b2, AI);
  gemm_hp<0><<<1024, 512, kLdsG, stream>>>(AI, w3i, b3, BI);

  gemm_dots_split<<<Bb * 8, 256, 0, stream>>>(qi, BI, dotsb);
  reduce_k<<<Bb, 256, 0, stream>>>(dotsb, s_j, s_all);
  attn_k<<<Bb * Ss, 256, 0, stream>>>(dotsb, s_j, s_all, out_attn, inv_r);
  updates_k2<<<Bb * 2, 256, kLdsU, stream>>>(out_attn, inputs, inv_r, out_updates);
}